// Round 4
// baseline (7681.917 us; speedup 1.0000x reference)
//
#include <hip/hip_runtime.h>
#include <hip/hip_fp16.h>
#include <stdint.h>

// ---------------------------------------------------------------------------
// StateRNN: masked LSTM (B=64,T=2048,H=256) + 3-layer MLP head.
// R4 design:
//  * phase1: 256 WGs x 512 thr, wh resident (192 VGPR-or-AGPR/thread +
//    128KB LDS). NEW: 4 tasks stepped in lockstep per step -> weight-access
//    cost (incl. any AGPR moves), s_w LDS reads, syncs and epilogue are
//    amortized 4x over the dot2 work; 16 independent acc chains for ILP.
//    xw staged 2 steps x 4 tasks (16KB LDS), refill GEMM every 2nd step.
//  * phase2: sequential prefix fill per batch row (unchanged).
//  * head: 64-row x 512-thread tiles (was 32x256): 2x compute per sync,
//    half the per-WG weight re-reads.
// ---------------------------------------------------------------------------

typedef _Float16 f16;
typedef _Float16 f16x2 __attribute__((ext_vector_type(2)));
typedef unsigned int u32;
typedef u32 u32x2 __attribute__((ext_vector_type(2)));
typedef u32 u32x4 __attribute__((ext_vector_type(4)));
typedef float f32x4 __attribute__((ext_vector_type(4)));

#define B_     64
#define T_     2048
#define NIN_   48
#define H_     256
#define G4_    1024
#define CH_    64
#define NCHUNK (T_ / CH_)       // 32
#define NTASK  (B_ * NCHUNK)    // 2048
#define P1_WG  256
#define TPG    4                // tasks per group (stepped in lockstep)
#define NROWS  (B_ * T_)        // 131072

__device__ __forceinline__ f16x2 as_h2(u32 u) { return __builtin_bit_cast(f16x2, u); }

__device__ __forceinline__ float dot2(u32 a, u32 b, float c) {
#if __has_builtin(__builtin_amdgcn_fdot2)
  return __builtin_amdgcn_fdot2(as_h2(a), as_h2(b), c, false);
#else
  f16x2 ah = as_h2(a), bh = as_h2(b);
  return c + (float)ah.x * (float)bh.x + (float)ah.y * (float)bh.y;
#endif
}

__device__ __forceinline__ float dot8(u32x4 a, u32x4 b, float acc) {
  acc = dot2(a.x, b.x, acc);
  acc = dot2(a.y, b.y, acc);
  acc = dot2(a.z, b.z, acc);
  acc = dot2(a.w, b.w, acc);
  return acc;
}

__device__ __forceinline__ u32x4 ld2x64(const f16* p) {
  u32x2 a = *(const u32x2*)p;
  u32x2 b = *(const u32x2*)(p + 4);
  u32x4 r; r.x = a.x; r.y = a.y; r.z = b.x; r.w = b.y;
  return r;
}

__device__ __forceinline__ float mix8(f32x4 x0, f32x4 x1, u32x4 wv, float acc) {
  f16x2 p;
  p = as_h2(wv.x); acc = fmaf((float)p.x, x0.x, acc); acc = fmaf((float)p.y, x0.y, acc);
  p = as_h2(wv.y); acc = fmaf((float)p.x, x0.z, acc); acc = fmaf((float)p.y, x0.w, acc);
  p = as_h2(wv.z); acc = fmaf((float)p.x, x1.x, acc); acc = fmaf((float)p.y, x1.y, acc);
  p = as_h2(wv.w); acc = fmaf((float)p.x, x1.z, acc); acc = fmaf((float)p.y, x1.w, acc);
  return acc;
}

__device__ __forceinline__ float sigmf(float x) {
  return 1.0f / (1.0f + __builtin_exp2f(-1.44269504f * x));
}
__device__ __forceinline__ float tanhf_(float x) {
  return 2.0f / (1.0f + __builtin_exp2f(-2.88539008f * x)) - 1.0f;
}

// ---------------------------------------------------------------------------
// K0: weights -> f16, transposed.
// ---------------------------------------------------------------------------
__global__ void k_prep(const float* __restrict__ wx, const float* __restrict__ wh,
                       const float* __restrict__ w1, const float* __restrict__ w2,
                       const float* __restrict__ w3,
                       f16* __restrict__ wxT, f16* __restrict__ whT,
                       f16* __restrict__ w1T, f16* __restrict__ w2T,
                       f16* __restrict__ w3T) {
  const int i0 = blockIdx.x * blockDim.x + threadIdx.x;
  const int stride = gridDim.x * blockDim.x;
  for (int idx = i0; idx < NIN_ * G4_; idx += stride) {
    int k = idx / G4_, c = idx % G4_;
    wxT[c * NIN_ + k] = (f16)wx[idx];
  }
  for (int idx = i0; idx < H_ * G4_; idx += stride) {
    int k = idx / G4_, c = idx % G4_;
    whT[c * H_ + k] = (f16)wh[idx];
  }
  for (int idx = i0; idx < 256 * 256; idx += stride) {
    int k = idx / 256, o = idx % 256;
    w1T[o * 256 + k] = (f16)w1[idx];
  }
  for (int idx = i0; idx < 256 * 128; idx += stride) {
    int k = idx / 128, o = idx % 128;
    w2T[o * 256 + k] = (f16)w2[idx];
  }
  for (int idx = i0; idx < 128 * 32; idx += stride) {
    int k = idx / 32, o = idx % 32;
    w3T[o * 128 + k] = (f16)w3[idx];
  }
}

// ---------------------------------------------------------------------------
// Phase 1: 4-task lockstep recurrence with resident weights.
// ---------------------------------------------------------------------------
__global__ __launch_bounds__(512, 1) void k_phase1(
    const float* __restrict__ seq, const float* __restrict__ mask,
    const f16* __restrict__ wxT, const f16* __restrict__ whT,
    const float* __restrict__ bias,
    f16* __restrict__ hs, float* __restrict__ carry) {
  __shared__ __attribute__((aligned(16))) u32x4 s_w[4 * 4 * 512];     // 128KB wh LDS share
  __shared__ __attribute__((aligned(16))) f16 s_xw[2][TPG][G4_];      // 16KB xw (2 steps x 4 tasks)
  __shared__ __attribute__((aligned(16))) f16 s_h[2][TPG][H_];        // 4KB h dbuf
  __shared__ __attribute__((aligned(16))) f16 s_xs[2 * TPG][NIN_];    // 768B x rows for refill
  __shared__ float s_m[TPG][CH_];                                     // 1KB

  const int tid = threadIdx.x;
  const int j = tid >> 1, q = tid & 1;

  // resident wh: per thread 4 gates x 128 k: 12 blocks reg + 4 blocks LDS
  u32x4 wreg[4][12];
#pragma unroll
  for (int g = 0; g < 4; ++g) {
    const f16* wp = whT + (size_t)(g * H_ + j) * H_ + q * 128;
#pragma unroll
    for (int kb = 0; kb < 12; ++kb) wreg[g][kb] = *(const u32x4*)(wp + kb * 8);
#pragma unroll
    for (int kb = 0; kb < 4; ++kb)
      s_w[(g * 4 + kb) * 512 + tid] = *(const u32x4*)(wp + 96 + kb * 8);
  }
  const int c0 = tid * 2;
  const float bia0 = bias[c0], bia1 = bias[c0 + 1];
  __syncthreads();

#pragma unroll 1
  for (int grp = 0; grp < 2; ++grp) {
    const int gt0 = blockIdx.x * (2 * TPG) + grp * TPG;  // 4 consecutive tasks, same b
    const int b = gt0 >> 5, ch0 = gt0 & 31;
    const int t00 = ch0 * CH_;

    // stage masks (4x64) and zero h buffers
    if (tid < TPG * CH_) s_m[tid >> 6][tid & 63] = mask[b * T_ + t00 + tid];
    ((u32*)s_h)[tid] = 0u;
    ((u32*)s_h)[512 + tid] = 0u;
    __syncthreads();

    float c_state[TPG] = {0.f, 0.f, 0.f, 0.f};
    float h_last[TPG] = {0.f, 0.f, 0.f, 0.f};

#pragma unroll 1
    for (int lt = 0; lt < CH_; ++lt) {
      const int sl = lt & 1;
      // ---- every 2 steps: refill s_xw rows for steps lt, lt+1 of 4 tasks ----
      if (sl == 0) {
        if (tid < 2 * TPG * NIN_) {
          const int r = tid / NIN_, k = tid % NIN_;
          const int ti = r >> 1, s = r & 1;
          s_xs[r][k] = (f16)seq[((size_t)b * T_ + t00 + ti * CH_ + lt + s) * NIN_ + k];
        }
        __syncthreads();
        float a0[8], a1[8];
#pragma unroll
        for (int rr = 0; rr < 8; ++rr) { a0[rr] = bia0; a1[rr] = bia1; }
#pragma unroll
        for (int kb = 0; kb < 6; ++kb) {
          u32x4 w0 = *(const u32x4*)(wxT + c0 * NIN_ + kb * 8);
          u32x4 w1 = *(const u32x4*)(wxT + (c0 + 1) * NIN_ + kb * 8);
#pragma unroll
          for (int rr = 0; rr < 8; ++rr) {
            u32x4 xv = *(const u32x4*)(&s_xs[rr][kb * 8]);
            a0[rr] = dot8(xv, w0, a0[rr]);
            a1[rr] = dot8(xv, w1, a1[rr]);
          }
        }
#pragma unroll
        for (int rr = 0; rr < 8; ++rr) {
          f16x2 o2; o2.x = (f16)a0[rr]; o2.y = (f16)a1[rr];
          *(f16x2*)(&s_xw[rr & 1][rr >> 1][c0]) = o2;
        }
        __syncthreads();
      }

      // ---- 4-task recurrent step ----
      float acc[TPG][4];
#pragma unroll
      for (int ti = 0; ti < TPG; ++ti)
#pragma unroll
        for (int g = 0; g < 4; ++g) acc[ti][g] = 0.f;

#pragma unroll
      for (int kb = 0; kb < 12; ++kb) {
#pragma unroll
        for (int ti = 0; ti < TPG; ++ti) {
          u32x4 hv = *(const u32x4*)(&s_h[sl][ti][q * 128 + kb * 8]);
#pragma unroll
          for (int g = 0; g < 4; ++g) acc[ti][g] = dot8(hv, wreg[g][kb], acc[ti][g]);
        }
      }
#pragma unroll
      for (int kb = 0; kb < 4; ++kb) {
        u32x4 hv2[TPG];
#pragma unroll
        for (int ti = 0; ti < TPG; ++ti)
          hv2[ti] = *(const u32x4*)(&s_h[sl][ti][q * 128 + 96 + kb * 8]);
#pragma unroll
        for (int g = 0; g < 4; ++g) {
          u32x4 wv = s_w[(g * 4 + kb) * 512 + tid];
#pragma unroll
          for (int ti = 0; ti < TPG; ++ti) acc[ti][g] = dot8(hv2[ti], wv, acc[ti][g]);
        }
      }

#pragma unroll
      for (int ti = 0; ti < TPG; ++ti) {
        const float keep = 1.0f - s_m[ti][lt];
#pragma unroll
        for (int g = 0; g < 4; ++g) {
          acc[ti][g] *= keep;                    // uniform within lane pair
          acc[ti][g] += __shfl_xor(acc[ti][g], 1);
        }
        const f16* xr = &s_xw[sl][ti][0];
        float z0 = acc[ti][0] + (float)xr[j];
        float z1 = acc[ti][1] + (float)xr[H_ + j];
        float z2 = acc[ti][2] + (float)xr[2 * H_ + j];
        float z3 = acc[ti][3] + (float)xr[3 * H_ + j];
        float ig = sigmf(z0), fg = sigmf(z1), og = sigmf(z2), ug = tanhf_(z3);
        c_state[ti] = fg * (keep * c_state[ti]) + ig * ug;
        const float hn = og * tanhf_(c_state[ti]);
        h_last[ti] = hn;
        if (q == 0) {
          s_h[sl ^ 1][ti][j] = (f16)hn;
          hs[((size_t)(t00 + ti * CH_ + lt) * B_ + b) * H_ + j] = (f16)hn;  // time-major
        }
      }
      __syncthreads();
    }
    if (q == 0) {
#pragma unroll
      for (int ti = 0; ti < TPG; ++ti) {
        carry[(size_t)(gt0 + ti) * 512 + j] = c_state[ti];
        carry[(size_t)(gt0 + ti) * 512 + H_ + j] = h_last[ti];
      }
    }
    __syncthreads();  // reads of s_m/s_h done before next group restages
  }
}

// ---------------------------------------------------------------------------
// Phase 2: 64 WGs (one per batch row). Fill prefixes [t0, t0+r) from the true
// carry; adopt phase-1 carry afterwards. Prefix steps have mask==0.
// ---------------------------------------------------------------------------
__global__ __launch_bounds__(512, 1) void k_phase2(
    const float* __restrict__ seq, const float* __restrict__ mask,
    const float* __restrict__ states_in,
    const f16* __restrict__ wxT, const f16* __restrict__ whT,
    const float* __restrict__ bias,
    const float* __restrict__ carry,
    f16* __restrict__ hs, float* __restrict__ out_states) {
  __shared__ __attribute__((aligned(16))) u32x4 s_w[4 * 4 * 512];
  __shared__ __attribute__((aligned(16))) f16 s_h[H_];
  __shared__ __attribute__((aligned(16))) float s_x48[NIN_];
  __shared__ int s_r;

  const int tid = threadIdx.x;
  const int j = tid >> 1, q = tid & 1;
  const int b = blockIdx.x;

  u32x4 wreg[4][12];
#pragma unroll
  for (int g = 0; g < 4; ++g) {
    const f16* wp = whT + (size_t)(g * H_ + j) * H_ + q * 128;
#pragma unroll
    for (int kb = 0; kb < 12; ++kb) wreg[g][kb] = *(const u32x4*)(wp + kb * 8);
#pragma unroll
    for (int kb = 0; kb < 4; ++kb)
      s_w[(g * 4 + kb) * 512 + tid] = *(const u32x4*)(wp + 96 + kb * 8);
  }
  if (tid < H_) s_h[tid] = (f16)states_in[b * 512 + H_ + tid];
  float c_state = states_in[b * 512 + j];
  float h_cur = states_in[b * 512 + H_ + j];
  const float bia[4] = {bias[j], bias[H_ + j], bias[2 * H_ + j], bias[3 * H_ + j]};
  __syncthreads();

  for (int ch = 0; ch < NCHUNK; ++ch) {
    const int t0 = ch * CH_;
    if (tid < 64) {
      float mv = mask[b * T_ + t0 + tid];
      unsigned long long bal = __ballot(mv != 0.0f);
      if (tid == 0) s_r = bal ? (__ffsll((unsigned long long)bal) - 1) : CH_;
    }
    __syncthreads();
    const int r = s_r;

    for (int t = t0; t < t0 + r; ++t) {  // prefix (mask==0 on all these steps)
      if (tid < NIN_) s_x48[tid] = seq[((size_t)b * T_ + t) * NIN_ + tid];
      __syncthreads();
      float acc[4] = {0.f, 0.f, 0.f, 0.f};
      const f16* hrow = &s_h[q * 128];
#pragma unroll
      for (int kb = 0; kb < 12; ++kb) {
        u32x4 hv = *(const u32x4*)(hrow + kb * 8);
#pragma unroll
        for (int g = 0; g < 4; ++g) acc[g] = dot8(hv, wreg[g][kb], acc[g]);
      }
#pragma unroll
      for (int kb = 0; kb < 4; ++kb) {
        u32x4 hv = *(const u32x4*)(hrow + 96 + kb * 8);
#pragma unroll
        for (int g = 0; g < 4; ++g)
          acc[g] = dot8(hv, s_w[(g * 4 + kb) * 512 + tid], acc[g]);
      }
#pragma unroll
      for (int kb = 0; kb < 3; ++kb) {
        f32x4 x0 = *(const f32x4*)(s_x48 + q * 24 + kb * 8);
        f32x4 x1 = *(const f32x4*)(s_x48 + q * 24 + kb * 8 + 4);
#pragma unroll
        for (int g = 0; g < 4; ++g) {
          u32x4 wv = *(const u32x4*)(wxT + (size_t)(g * H_ + j) * NIN_ + q * 24 + kb * 8);
          acc[g] = mix8(x0, x1, wv, acc[g]);
        }
      }
#pragma unroll
      for (int g = 0; g < 4; ++g) acc[g] += __shfl_xor(acc[g], 1);
      float z0 = acc[0] + bia[0], z1 = acc[1] + bia[1];
      float z2 = acc[2] + bia[2], z3 = acc[3] + bia[3];
      float ig = sigmf(z0), fg = sigmf(z1), og = sigmf(z2), ug = tanhf_(z3);
      c_state = fg * c_state + ig * ug;
      const float hn = og * tanhf_(c_state);
      h_cur = hn;
      __syncthreads();
      if (q == 0) {
        s_h[j] = (f16)hn;
        hs[((size_t)t * B_ + b) * H_ + j] = (f16)hn;
      }
      __syncthreads();
    }

    if (r < CH_) {  // adopt exact phase-1 carry
      const int gtask = b * NCHUNK + ch;
      c_state = carry[(size_t)gtask * 512 + j];
      h_cur = carry[(size_t)gtask * 512 + H_ + j];
      __syncthreads();
      if (tid < H_) s_h[tid] = (f16)carry[(size_t)gtask * 512 + H_ + tid];
      __syncthreads();
    }
  }
  if (q == 0) {
    out_states[b * 512 + j] = c_state;
    out_states[b * 512 + H_ + j] = h_cur;
  }
}

// ---------------------------------------------------------------------------
// Head: fused 3-layer MLP over 64-row tiles of flat [T*B, H], 512 threads.
// ---------------------------------------------------------------------------
#define K3R 64
__global__ __launch_bounds__(512, 1) void k_head(
    const f16* __restrict__ hs,
    const f16* __restrict__ w1T, const float* __restrict__ b1,
    const f16* __restrict__ w2T, const float* __restrict__ b2,
    const f16* __restrict__ w3T, const float* __restrict__ b3,
    float* __restrict__ out) {
  __shared__ __attribute__((aligned(16))) f16 s_xx[K3R * 256];   // 32KB
  __shared__ __attribute__((aligned(16))) f16 s_d1[K3R * 256];   // 32KB
  __shared__ __attribute__((aligned(16))) f16 s_d2[K3R * 128];   // 16KB
  __shared__ __attribute__((aligned(16))) f16 s_wst[256 * 20];   // 10KB padded stage
  __shared__ __attribute__((aligned(16))) f16 s_w3[32 * 136];    // 8.5KB padded
  __shared__ float s_b1[256];
  __shared__ float s_b2[128];
  __shared__ float s_b3[32];

  const int tid = threadIdx.x;
  const size_t row0 = (size_t)blockIdx.x * K3R;

  {
    const u32x4* src = (const u32x4*)(hs + row0 * 256);
    u32x4* dst = (u32x4*)s_xx;
    for (int i = tid; i < K3R * 256 / 8; i += 512) dst[i] = src[i];
  }
  for (int i = tid; i < 32 * 128; i += 512) {
    int c = i / 128, k = i % 128;
    s_w3[c * 136 + k] = w3T[i];
  }
  if (tid < 256) s_b1[tid] = b1[tid];
  if (tid < 128) s_b2[tid] = b2[tid];
  if (tid < 32) s_b3[tid] = b3[tid];

  // ---- L1: [64,256] @ [256->256]
  {
    const int rb = tid >> 5;   // 16 row blocks x4
    const int cb = tid & 31;   // 32 col blocks x8
    float acc[4][8];
#pragma unroll
    for (int rr = 0; rr < 4; ++rr)
#pragma unroll
      for (int cc = 0; cc < 8; ++cc) acc[rr][cc] = 0.f;
    for (int ks = 0; ks < 16; ++ks) {
      __syncthreads();
      {  // stage w1T[:, ks*16..+16] -> s_wst stride 20 (512 thr: c=tid>>1, half=tid&1)
        const int c = tid >> 1, half = tid & 1;
        u32x4 a = *(const u32x4*)(w1T + (size_t)c * 256 + ks * 16 + half * 8);
        u32x2* wdst = (u32x2*)(s_wst + c * 20 + half * 8);
        u32x2 p0; p0.x = a.x; p0.y = a.y;
        u32x2 p1; p1.x = a.z; p1.y = a.w;
        wdst[0] = p0; wdst[1] = p1;
      }
      __syncthreads();
#pragma unroll
      for (int kb = 0; kb < 2; ++kb) {
        u32x4 xv[4];
#pragma unroll
        for (int rr = 0; rr < 4; ++rr)
          xv[rr] = *(const u32x4*)(s_xx + (rb * 4 + rr) * 256 + ks * 16 + kb * 8);
#pragma unroll
        for (int cc = 0; cc < 8; ++cc) {
          u32x4 wv = ld2x64(s_wst + (cb * 8 + cc) * 20 + kb * 8);
#pragma unroll
          for (int rr = 0; rr < 4; ++rr) acc[rr][cc] = dot8(xv[rr], wv, acc[rr][cc]);
        }
      }
    }
    __syncthreads();
#pragma unroll
    for (int rr = 0; rr < 4; ++rr)
#pragma unroll
      for (int cc = 0; cc < 8; ++cc) {
        float v = acc[rr][cc] + s_b1[cb * 8 + cc];
        s_d1[(rb * 4 + rr) * 256 + cb * 8 + cc] = (f16)fmaxf(v, 0.f);
      }
  }
  __syncthreads();

  // ---- L2: [64,256] @ [256->128]
  {
    const int rb = tid >> 4;   // 32 row blocks x2
    const int cb = tid & 15;   // 16 col blocks x8
    float acc[2][8];
#pragma unroll
    for (int rr = 0; rr < 2; ++rr)
#pragma unroll
      for (int cc = 0; cc < 8; ++cc) acc[rr][cc] = 0.f;
    for (int ks = 0; ks < 16; ++ks) {
      __syncthreads();
      if (tid < 256) {  // 128 cols: c=tid>>1, half=tid&1
        const int c = tid >> 1, half = tid & 1;
        u32x4 a = *(const u32x4*)(w2T + (size_t)c * 256 + ks * 16 + half * 8);
        u32x2* wdst = (u32x2*)(s_wst + c * 20 + half * 8);
        u32x2 p0; p0.x = a.x; p0.y = a.y;
        u32x2 p1; p1.x = a.z; p1.y = a.w;
        wdst[0] = p0; wdst[1] = p1;
      }
      __syncthreads();
#pragma unroll
      for (int kb = 0; kb < 2; ++kb) {
        u32x4 xv[2];
#pragma unroll
        for (int rr = 0; rr < 2; ++rr)
          xv[rr] = *(const u32x4*)(s_d1 + (rb * 2 + rr) * 256 + ks * 16 + kb * 8);
#pragma unroll
        for (int cc = 0; cc < 8; ++cc) {
          u32x4 wv = ld2x64(s_wst + (cb * 8 + cc) * 20 + kb * 8);
#pragma unroll
          for (int rr = 0; rr < 2; ++rr) acc[rr][cc] = dot8(xv[rr], wv, acc[rr][cc]);
        }
      }
    }
    __syncthreads();
#pragma unroll
    for (int rr = 0; rr < 2; ++rr)
#pragma unroll
      for (int cc = 0; cc < 8; ++cc) {
        float v = acc[rr][cc] + s_b2[cb * 8 + cc];
        s_d2[(rb * 2 + rr) * 128 + cb * 8 + cc] = (f16)fmaxf(v, 0.f);
      }
  }
  __syncthreads();

  // ---- L3: [64,128] @ [128->32] -> out (f32)
  {
    const int r = tid >> 3;    // 64 rows
    const int cg = tid & 7;    // 8 col groups x4
    float acc[4] = {0.f, 0.f, 0.f, 0.f};
#pragma unroll
    for (int kb = 0; kb < 16; ++kb) {
      u32x4 xv = *(const u32x4*)(s_d2 + r * 128 + kb * 8);
#pragma unroll
      for (int cc = 0; cc < 4; ++cc) {
        u32x4 wv = *(const u32x4*)(s_w3 + (cg * 4 + cc) * 136 + kb * 8);
        acc[cc] = dot8(xv, wv, acc[cc]);
      }
    }
    f32x4 o;
    o.x = acc[0] + s_b3[cg * 4 + 0];
    o.y = acc[1] + s_b3[cg * 4 + 1];
    o.z = acc[2] + s_b3[cg * 4 + 2];
    o.w = acc[3] + s_b3[cg * 4 + 3];
    *(f32x4*)(out + (row0 + r) * 32 + cg * 4) = o;
  }
}

// ---------------------------------------------------------------------------
extern "C" void kernel_launch(void* const* d_in, const int* in_sizes, int n_in,
                              void* d_out, int out_size, void* d_ws, size_t ws_size,
                              hipStream_t stream) {
  const float* seq = (const float*)d_in[0];
  const float* mask = (const float*)d_in[1];
  const float* st = (const float*)d_in[2];
  const float* wx = (const float*)d_in[3];
  const float* wh = (const float*)d_in[4];
  const float* bz = (const float*)d_in[5];
  const float* w1 = (const float*)d_in[6];
  const float* b1 = (const float*)d_in[7];
  const float* w2 = (const float*)d_in[8];
  const float* b2 = (const float*)d_in[9];
  const float* w3 = (const float*)d_in[10];
  const float* b3 = (const float*)d_in[11];
  float* out = (float*)d_out;

  char* ws = (char*)d_ws;
  size_t off = 0;
  auto take = [&](size_t bytes) {
    void* p = ws + off;
    off = (off + bytes + 255) & ~(size_t)255;
    return p;
  };
  f16* wxT = (f16*)take((size_t)G4_ * NIN_ * 2);
  f16* whT = (f16*)take((size_t)G4_ * H_ * 2);
  f16* w1T = (f16*)take((size_t)256 * 256 * 2);
  f16* w2T = (f16*)take((size_t)128 * 256 * 2);
  f16* w3T = (f16*)take((size_t)32 * 128 * 2);
  float* carry = (float*)take((size_t)NTASK * 512 * 4);
  f16* hsb = (f16*)take((size_t)NROWS * H_ * 2);
  (void)ws_size; (void)in_sizes; (void)n_in; (void)out_size;

  k_prep<<<dim3(512), dim3(256), 0, stream>>>(wx, wh, w1, w2, w3, wxT, whT, w1T, w2T, w3T);
  k_phase1<<<dim3(P1_WG), dim3(512), 0, stream>>>(seq, mask, wxT, whT, bz, hsb, carry);
  k_phase2<<<dim3(B_), dim3(512), 0, stream>>>(seq, mask, st, wxT, whT, bz, carry, hsb,
                                               out + (size_t)B_ * T_ * 32);
  k_head<<<dim3(NROWS / K3R), dim3(512), 0, stream>>>(hsb, w1T, b1, w2T, b2, w3T, b3, out);
}

// Round 5
// 2354.712 us; speedup vs baseline: 3.2624x; 3.2624x over previous
//
#include <hip/hip_runtime.h>
#include <hip/hip_fp16.h>
#include <stdint.h>

// ---------------------------------------------------------------------------
// StateRNN: masked LSTM (B=64,T=2048,H=256) + 3-layer MLP head.
// R5 design:
//  * phase1 -> MFMA. 128 WGs x 16 tasks; per step the WG computes
//    z[16,1024] = x@wx + keep*(h@wh) + b via mfma_f32_16x16x32_f16.
//    wh streamed from L2 every step in frag-major layout (whF); wx frags
//    register-resident; h/x in XOR-swizzled LDS; gates fully in-register
//    (wave owns 32 units x 4 gates -> lane holds complete i,f,o,u sets).
//    R4's register-resident dot2 design spilled to scratch (FETCH 18.6GB).
//  * phase2: sequential prefix fill per batch row (unchanged).
//  * head: 64-row fused MLP tiles (unchanged from R4).
// ---------------------------------------------------------------------------

typedef _Float16 f16;
typedef _Float16 f16x2 __attribute__((ext_vector_type(2)));
typedef _Float16 f16x8 __attribute__((ext_vector_type(8)));
typedef unsigned int u32;
typedef u32 u32x2 __attribute__((ext_vector_type(2)));
typedef u32 u32x4 __attribute__((ext_vector_type(4)));
typedef float f32x4 __attribute__((ext_vector_type(4)));

#define B_     64
#define T_     2048
#define NIN_   48
#define H_     256
#define G4_    1024
#define CH_    64
#define NCHUNK (T_ / CH_)       // 32
#define NTASK  (B_ * NCHUNK)    // 2048
#define MT     16               // tasks per WG (one mfma M-tile)
#define P1_NWG (NTASK / MT)     // 128
#define NROWS  (B_ * T_)        // 131072

__device__ __forceinline__ f16x2 as_h2(u32 u) { return __builtin_bit_cast(f16x2, u); }

__device__ __forceinline__ float dot2(u32 a, u32 b, float c) {
#if __has_builtin(__builtin_amdgcn_fdot2)
  return __builtin_amdgcn_fdot2(as_h2(a), as_h2(b), c, false);
#else
  f16x2 ah = as_h2(a), bh = as_h2(b);
  return c + (float)ah.x * (float)bh.x + (float)ah.y * (float)bh.y;
#endif
}

__device__ __forceinline__ float dot8(u32x4 a, u32x4 b, float acc) {
  acc = dot2(a.x, b.x, acc);
  acc = dot2(a.y, b.y, acc);
  acc = dot2(a.z, b.z, acc);
  acc = dot2(a.w, b.w, acc);
  return acc;
}

__device__ __forceinline__ u32x4 ld2x64(const f16* p) {
  u32x2 a = *(const u32x2*)p;
  u32x2 b = *(const u32x2*)(p + 4);
  u32x4 r; r.x = a.x; r.y = a.y; r.z = b.x; r.w = b.y;
  return r;
}

__device__ __forceinline__ float mix8(f32x4 x0, f32x4 x1, u32x4 wv, float acc) {
  f16x2 p;
  p = as_h2(wv.x); acc = fmaf((float)p.x, x0.x, acc); acc = fmaf((float)p.y, x0.y, acc);
  p = as_h2(wv.y); acc = fmaf((float)p.x, x0.z, acc); acc = fmaf((float)p.y, x0.w, acc);
  p = as_h2(wv.z); acc = fmaf((float)p.x, x1.x, acc); acc = fmaf((float)p.y, x1.y, acc);
  p = as_h2(wv.w); acc = fmaf((float)p.x, x1.z, acc); acc = fmaf((float)p.y, x1.w, acc);
  return acc;
}

__device__ __forceinline__ float sigmf(float x) {
  return 1.0f / (1.0f + __builtin_exp2f(-1.44269504f * x));
}
__device__ __forceinline__ float tanhf_(float x) {
  return 2.0f / (1.0f + __builtin_exp2f(-2.88539008f * x)) - 1.0f;
}

// ---------------------------------------------------------------------------
// K0: weight conversion/shuffles.
//  wxT[c][k] (1024x48)  whT[c][k] (1024x256)        -- phase2 dot2 path
//  whF[w][kt][ct][l][8] (8*8*8*64*8 f16 = 512KB)    -- phase1 mfma B frags
//  wxF[w][kt2][ct][l][8] (8*2*8*64*8 f16 = 128KB)   -- phase1 x B frags
//  w1T/w2T/w3T                                       -- head
// Frag mapping (mfma_f32_16x16x32_f16): B col = lane&15, k = (lane>>4)*8+j.
// Wave w owns cols {g*256 + w*32 + s*16 + c}, ct = g*2+s.
// ---------------------------------------------------------------------------
__global__ void k_prep(const float* __restrict__ wx, const float* __restrict__ wh,
                       const float* __restrict__ w1, const float* __restrict__ w2,
                       const float* __restrict__ w3,
                       f16* __restrict__ wxT, f16* __restrict__ whT,
                       f16* __restrict__ w1T, f16* __restrict__ w2T,
                       f16* __restrict__ w3T,
                       f16* __restrict__ whF, f16* __restrict__ wxF) {
  const int i0 = blockIdx.x * blockDim.x + threadIdx.x;
  const int stride = gridDim.x * blockDim.x;
  for (int idx = i0; idx < NIN_ * G4_; idx += stride) {
    int k = idx / G4_, c = idx % G4_;
    wxT[c * NIN_ + k] = (f16)wx[idx];
  }
  for (int idx = i0; idx < H_ * G4_; idx += stride) {
    int k = idx / G4_, c = idx % G4_;
    whT[c * H_ + k] = (f16)wh[idx];
  }
  // whF: idx = ((((w*8+kt)*8+ct)*64)+l)*8 + j
  for (int idx = i0; idx < 8 * 8 * 8 * 64 * 8; idx += stride) {
    int j = idx & 7, l = (idx >> 3) & 63, ct = (idx >> 9) & 7;
    int kt = (idx >> 12) & 7, w = idx >> 15;
    int col = (ct >> 1) * 256 + w * 32 + (ct & 1) * 16 + (l & 15);
    int k = kt * 32 + (l >> 4) * 8 + j;
    whF[idx] = (f16)wh[k * G4_ + col];
  }
  // wxF: idx = ((((w*2+kt2)*8+ct)*64)+l)*8 + j  (k>=48 zero-padded)
  for (int idx = i0; idx < 8 * 2 * 8 * 64 * 8; idx += stride) {
    int j = idx & 7, l = (idx >> 3) & 63, ct = (idx >> 9) & 7;
    int kt2 = (idx >> 12) & 1, w = idx >> 13;
    int col = (ct >> 1) * 256 + w * 32 + (ct & 1) * 16 + (l & 15);
    int k = kt2 * 32 + (l >> 4) * 8 + j;
    wxF[idx] = (k < NIN_) ? (f16)wx[k * G4_ + col] : (f16)0.f;
  }
  for (int idx = i0; idx < 256 * 256; idx += stride) {
    int k = idx / 256, o = idx % 256;
    w1T[o * 256 + k] = (f16)w1[idx];
  }
  for (int idx = i0; idx < 256 * 128; idx += stride) {
    int k = idx / 128, o = idx % 128;
    w2T[o * 256 + k] = (f16)w2[idx];
  }
  for (int idx = i0; idx < 128 * 32; idx += stride) {
    int k = idx / 32, o = idx % 32;
    w3T[o * 128 + k] = (f16)w3[idx];
  }
}

// ---------------------------------------------------------------------------
// Phase 1 (MFMA): 128 WGs x 512 thr, 16 tasks each, 64 steps from zero state.
// ---------------------------------------------------------------------------
__global__ __launch_bounds__(512, 1) void k_phase1(
    const float* __restrict__ seq, const float* __restrict__ mask,
    const f16* __restrict__ whF, const f16* __restrict__ wxF,
    const float* __restrict__ bias,
    f16* __restrict__ hs, float* __restrict__ carry) {
  __shared__ __attribute__((aligned(16))) f16 s_h[MT * 256];     // 8KB, swizzled
  __shared__ __attribute__((aligned(16))) f16 s_x[8 * MT * 64];  // 16KB, swizzled
  __shared__ float s_m[CH_][MT];                                 // 4KB [lt][task]

  const int tid = threadIdx.x;
  const int wv = tid >> 6, l = tid & 63;
  const int l15 = l & 15, lq = l >> 4;
  const int gt0 = blockIdx.x * MT;
  char* s_hb = (char*)s_h;
  char* s_xb = (char*)s_x;

  // resident wx B-fragments (8 col-tiles x 2 k-tiles)
  f16x8 wxf[2][8];
#pragma unroll
  for (int kt2 = 0; kt2 < 2; ++kt2)
#pragma unroll
    for (int ct = 0; ct < 8; ++ct)
      wxf[kt2][ct] = *(const f16x8*)(wxF + ((((size_t)wv * 2 + kt2) * 8 + ct) * 64 + l) * 8);

  float biasv[8];
#pragma unroll
  for (int ct = 0; ct < 8; ++ct)
    biasv[ct] = bias[(ct >> 1) * 256 + wv * 32 + (ct & 1) * 16 + l15];

  // stage masks [lt][task]
  for (int i = tid; i < CH_ * MT; i += 512) {
    int task = i & 15, lt = i >> 4;
    int gt = gt0 + task, b = gt >> 5, ch = gt & 31;
    s_m[lt][task] = mask[b * T_ + ch * CH_ + lt];
  }
  for (int i = tid; i < MT * 256 / 2; i += 512) ((u32*)s_h)[i] = 0u;

  float c_st[8] = {0.f, 0.f, 0.f, 0.f, 0.f, 0.f, 0.f, 0.f};
  float h_st[8] = {0.f, 0.f, 0.f, 0.f, 0.f, 0.f, 0.f, 0.f};

  const int unit0 = wv * 32 + l15;
  int tr_b[4], tr_t0[4];
#pragma unroll
  for (int r = 0; r < 4; ++r) {
    int gt = gt0 + lq * 4 + r;
    tr_b[r] = gt >> 5;
    tr_t0[r] = (gt & 31) * CH_;
  }
  __syncthreads();

  for (int lt = 0; lt < CH_; ++lt) {
    // ---- every 8 steps: refill x window (f16, zero-padded k 48..63) ----
    if ((lt & 7) == 0) {
      const int s2 = tid >> 6, task = (tid >> 2) & 15, kq = tid & 3;
      const int gt = gt0 + task, b = gt >> 5, ch = gt & 31;
      const int t = ch * CH_ + lt + s2;
      f16 tmp[16];
      if (kq < 3) {
        const float* xp = seq + ((size_t)b * T_ + t) * NIN_ + kq * 16;
#pragma unroll
        for (int u = 0; u < 16; ++u) tmp[u] = (f16)xp[u];
      } else {
#pragma unroll
        for (int u = 0; u < 16; ++u) tmp[u] = (f16)0.f;
      }
      const int eb = (s2 * MT + task) * 64 + kq * 16;
      const int swz = (task & 7) << 4;
      *(u32x4*)(s_xb + ((eb * 2) ^ swz)) = ((u32x4*)tmp)[0];
      *(u32x4*)(s_xb + (((eb + 8) * 2) ^ swz)) = ((u32x4*)tmp)[1];
      __syncthreads();
    }

    // ---- GEMM step: C = bias; += keep*h @ wh; += x @ wx ----
    f32x4 C[8];
#pragma unroll
    for (int ct = 0; ct < 8; ++ct) {
      C[ct].x = biasv[ct]; C[ct].y = biasv[ct];
      C[ct].z = biasv[ct]; C[ct].w = biasv[ct];
    }

    const float keep_a = 1.0f - s_m[lt][l15];  // A-row (task) keep
    f16x8 ka8;
#pragma unroll
    for (int u = 0; u < 8; ++u) ka8[u] = (f16)keep_a;

    const int hswz = (l15 & 7) << 4;
#pragma unroll
    for (int kt = 0; kt < 8; ++kt) {
      u32x4 araw = *(const u32x4*)(s_hb + l15 * 512 + (((kt * 32 + lq * 8) * 2) ^ hswz));
      f16x8 av = __builtin_bit_cast(f16x8, araw) * ka8;
#pragma unroll
      for (int ct = 0; ct < 8; ++ct) {
        f16x8 bv = *(const f16x8*)(whF + ((((size_t)wv * 8 + kt) * 8 + ct) * 64 + l) * 8);
        C[ct] = __builtin_amdgcn_mfma_f32_16x16x32_f16(av, bv, C[ct], 0, 0, 0);
      }
    }
    const int s2w = lt & 7;
#pragma unroll
    for (int kt2 = 0; kt2 < 2; ++kt2) {
      u32x4 araw = *(const u32x4*)(
          s_xb + ((((s2w * MT + l15) * 64 + kt2 * 32 + lq * 8) * 2) ^ hswz));
      f16x8 av = __builtin_bit_cast(f16x8, araw);
#pragma unroll
      for (int ct = 0; ct < 8; ++ct)
        C[ct] = __builtin_amdgcn_mfma_f32_16x16x32_f16(av, wxf[kt2][ct], C[ct], 0, 0, 0);
    }
    __syncthreads();  // all A-frag reads done before h overwrite

    // ---- epilogue: gates fully in-register ----
    float kc[4];
#pragma unroll
    for (int r = 0; r < 4; ++r) kc[r] = 1.0f - s_m[lt][lq * 4 + r];
#pragma unroll
    for (int s = 0; s < 2; ++s)
#pragma unroll
      for (int r = 0; r < 4; ++r) {
        const int ci = s * 4 + r;
        float zi = C[0 + s][r], zf = C[2 + s][r], zo = C[4 + s][r], zu = C[6 + s][r];
        float ig = sigmf(zi), fg = sigmf(zf), og = sigmf(zo), ug = tanhf_(zu);
        c_st[ci] = fg * (kc[r] * c_st[ci]) + ig * ug;
        const float hn = og * tanhf_(c_st[ci]);
        h_st[ci] = hn;
        const int unit = unit0 + s * 16;
        const int tr = lq * 4 + r;
        *(f16*)(s_hb + tr * 512 + ((unit * 2) ^ ((tr & 7) << 4))) = (f16)hn;
        hs[((size_t)(tr_t0[r] + lt) * B_ + tr_b[r]) * H_ + unit] = (f16)hn;
      }
    __syncthreads();
  }

#pragma unroll
  for (int s = 0; s < 2; ++s)
#pragma unroll
    for (int r = 0; r < 4; ++r) {
      const int gt = gt0 + lq * 4 + r;
      const int unit = unit0 + s * 16;
      carry[(size_t)gt * 512 + unit] = c_st[s * 4 + r];
      carry[(size_t)gt * 512 + 256 + unit] = h_st[s * 4 + r];
    }
}

// ---------------------------------------------------------------------------
// Phase 2: 64 WGs (one per batch row). Fill prefixes [t0, t0+r) from the true
// carry; adopt phase-1 carry afterwards. Prefix steps have mask==0.
// ---------------------------------------------------------------------------
__global__ __launch_bounds__(512, 1) void k_phase2(
    const float* __restrict__ seq, const float* __restrict__ mask,
    const float* __restrict__ states_in,
    const f16* __restrict__ wxT, const f16* __restrict__ whT,
    const float* __restrict__ bias,
    const float* __restrict__ carry,
    f16* __restrict__ hs, float* __restrict__ out_states) {
  __shared__ __attribute__((aligned(16))) u32x4 s_w[4 * 4 * 512];
  __shared__ __attribute__((aligned(16))) f16 s_h[H_];
  __shared__ __attribute__((aligned(16))) float s_x48[NIN_];
  __shared__ int s_r;

  const int tid = threadIdx.x;
  const int j = tid >> 1, q = tid & 1;
  const int b = blockIdx.x;

  u32x4 wreg[4][12];
#pragma unroll
  for (int g = 0; g < 4; ++g) {
    const f16* wp = whT + (size_t)(g * H_ + j) * H_ + q * 128;
#pragma unroll
    for (int kb = 0; kb < 12; ++kb) wreg[g][kb] = *(const u32x4*)(wp + kb * 8);
#pragma unroll
    for (int kb = 0; kb < 4; ++kb)
      s_w[(g * 4 + kb) * 512 + tid] = *(const u32x4*)(wp + 96 + kb * 8);
  }
  if (tid < H_) s_h[tid] = (f16)states_in[b * 512 + H_ + tid];
  float c_state = states_in[b * 512 + j];
  float h_cur = states_in[b * 512 + H_ + j];
  const float bia[4] = {bias[j], bias[H_ + j], bias[2 * H_ + j], bias[3 * H_ + j]};
  __syncthreads();

  for (int ch = 0; ch < NCHUNK; ++ch) {
    const int t0 = ch * CH_;
    if (tid < 64) {
      float mv = mask[b * T_ + t0 + tid];
      unsigned long long bal = __ballot(mv != 0.0f);
      if (tid == 0) s_r = bal ? (__ffsll((unsigned long long)bal) - 1) : CH_;
    }
    __syncthreads();
    const int r = s_r;

    for (int t = t0; t < t0 + r; ++t) {  // prefix (mask==0 on all these steps)
      if (tid < NIN_) s_x48[tid] = seq[((size_t)b * T_ + t) * NIN_ + tid];
      __syncthreads();
      float acc[4] = {0.f, 0.f, 0.f, 0.f};
      const f16* hrow = &s_h[q * 128];
#pragma unroll
      for (int kb = 0; kb < 12; ++kb) {
        u32x4 hv = *(const u32x4*)(hrow + kb * 8);
#pragma unroll
        for (int g = 0; g < 4; ++g) acc[g] = dot8(hv, wreg[g][kb], acc[g]);
      }
#pragma unroll
      for (int kb = 0; kb < 4; ++kb) {
        u32x4 hv = *(const u32x4*)(hrow + 96 + kb * 8);
#pragma unroll
        for (int g = 0; g < 4; ++g)
          acc[g] = dot8(hv, s_w[(g * 4 + kb) * 512 + tid], acc[g]);
      }
#pragma unroll
      for (int kb = 0; kb < 3; ++kb) {
        f32x4 x0 = *(const f32x4*)(s_x48 + q * 24 + kb * 8);
        f32x4 x1 = *(const f32x4*)(s_x48 + q * 24 + kb * 8 + 4);
#pragma unroll
        for (int g = 0; g < 4; ++g) {
          u32x4 wv = *(const u32x4*)(wxT + (size_t)(g * H_ + j) * NIN_ + q * 24 + kb * 8);
          acc[g] = mix8(x0, x1, wv, acc[g]);
        }
      }
#pragma unroll
      for (int g = 0; g < 4; ++g) acc[g] += __shfl_xor(acc[g], 1);
      float z0 = acc[0] + bia[0], z1 = acc[1] + bia[1];
      float z2 = acc[2] + bia[2], z3 = acc[3] + bia[3];
      float ig = sigmf(z0), fg = sigmf(z1), og = sigmf(z2), ug = tanhf_(z3);
      c_state = fg * c_state + ig * ug;
      const float hn = og * tanhf_(c_state);
      h_cur = hn;
      __syncthreads();
      if (q == 0) {
        s_h[j] = (f16)hn;
        hs[((size_t)t * B_ + b) * H_ + j] = (f16)hn;
      }
      __syncthreads();
    }

    if (r < CH_) {  // adopt exact phase-1 carry
      const int gtask = b * NCHUNK + ch;
      c_state = carry[(size_t)gtask * 512 + j];
      h_cur = carry[(size_t)gtask * 512 + 256 + j];
      __syncthreads();
      if (tid < H_) s_h[tid] = (f16)carry[(size_t)gtask * 512 + 256 + tid];
      __syncthreads();
    }
  }
  if (q == 0) {
    out_states[b * 512 + j] = c_state;
    out_states[b * 512 + H_ + j] = h_cur;
  }
}

// ---------------------------------------------------------------------------
// Head: fused 3-layer MLP over 64-row tiles of flat [T*B, H], 512 threads.
// ---------------------------------------------------------------------------
#define K3R 64
__global__ __launch_bounds__(512, 1) void k_head(
    const f16* __restrict__ hs,
    const f16* __restrict__ w1T, const float* __restrict__ b1,
    const f16* __restrict__ w2T, const float* __restrict__ b2,
    const f16* __restrict__ w3T, const float* __restrict__ b3,
    float* __restrict__ out) {
  __shared__ __attribute__((aligned(16))) f16 s_xx[K3R * 256];   // 32KB
  __shared__ __attribute__((aligned(16))) f16 s_d1[K3R * 256];   // 32KB
  __shared__ __attribute__((aligned(16))) f16 s_d2[K3R * 128];   // 16KB
  __shared__ __attribute__((aligned(16))) f16 s_wst[256 * 20];   // 10KB padded stage
  __shared__ __attribute__((aligned(16))) f16 s_w3[32 * 136];    // 8.5KB padded
  __shared__ float s_b1[256];
  __shared__ float s_b2[128];
  __shared__ float s_b3[32];

  const int tid = threadIdx.x;
  const size_t row0 = (size_t)blockIdx.x * K3R;

  {
    const u32x4* src = (const u32x4*)(hs + row0 * 256);
    u32x4* dst = (u32x4*)s_xx;
    for (int i = tid; i < K3R * 256 / 8; i += 512) dst[i] = src[i];
  }
  for (int i = tid; i < 32 * 128; i += 512) {
    int c = i / 128, k = i % 128;
    s_w3[c * 136 + k] = w3T[i];
  }
  if (tid < 256) s_b1[tid] = b1[tid];
  if (tid < 128) s_b2[tid] = b2[tid];
  if (tid < 32) s_b3[tid] = b3[tid];

  // ---- L1: [64,256] @ [256->256]
  {
    const int rb = tid >> 5;
    const int cb = tid & 31;
    float acc[4][8];
#pragma unroll
    for (int rr = 0; rr < 4; ++rr)
#pragma unroll
      for (int cc = 0; cc < 8; ++cc) acc[rr][cc] = 0.f;
    for (int ks = 0; ks < 16; ++ks) {
      __syncthreads();
      {
        const int c = tid >> 1, half = tid & 1;
        u32x4 a = *(const u32x4*)(w1T + (size_t)c * 256 + ks * 16 + half * 8);
        u32x2* wdst = (u32x2*)(s_wst + c * 20 + half * 8);
        u32x2 p0; p0.x = a.x; p0.y = a.y;
        u32x2 p1; p1.x = a.z; p1.y = a.w;
        wdst[0] = p0; wdst[1] = p1;
      }
      __syncthreads();
#pragma unroll
      for (int kb = 0; kb < 2; ++kb) {
        u32x4 xv[4];
#pragma unroll
        for (int rr = 0; rr < 4; ++rr)
          xv[rr] = *(const u32x4*)(s_xx + (rb * 4 + rr) * 256 + ks * 16 + kb * 8);
#pragma unroll
        for (int cc = 0; cc < 8; ++cc) {
          u32x4 wv = ld2x64(s_wst + (cb * 8 + cc) * 20 + kb * 8);
#pragma unroll
          for (int rr = 0; rr < 4; ++rr) acc[rr][cc] = dot8(xv[rr], wv, acc[rr][cc]);
        }
      }
    }
    __syncthreads();
#pragma unroll
    for (int rr = 0; rr < 4; ++rr)
#pragma unroll
      for (int cc = 0; cc < 8; ++cc) {
        float v = acc[rr][cc] + s_b1[cb * 8 + cc];
        s_d1[(rb * 4 + rr) * 256 + cb * 8 + cc] = (f16)fmaxf(v, 0.f);
      }
  }
  __syncthreads();

  // ---- L2: [64,256] @ [256->128]
  {
    const int rb = tid >> 4;
    const int cb = tid & 15;
    float acc[2][8];
#pragma unroll
    for (int rr = 0; rr < 2; ++rr)
#pragma unroll
      for (int cc = 0; cc < 8; ++cc) acc[rr][cc] = 0.f;
    for (int ks = 0; ks < 16; ++ks) {
      __syncthreads();
      if (tid < 256) {
        const int c = tid >> 1, half = tid & 1;
        u32x4 a = *(const u32x4*)(w2T + (size_t)c * 256 + ks * 16 + half * 8);
        u32x2* wdst = (u32x2*)(s_wst + c * 20 + half * 8);
        u32x2 p0; p0.x = a.x; p0.y = a.y;
        u32x2 p1; p1.x = a.z; p1.y = a.w;
        wdst[0] = p0; wdst[1] = p1;
      }
      __syncthreads();
#pragma unroll
      for (int kb = 0; kb < 2; ++kb) {
        u32x4 xv[2];
#pragma unroll
        for (int rr = 0; rr < 2; ++rr)
          xv[rr] = *(const u32x4*)(s_d1 + (rb * 2 + rr) * 256 + ks * 16 + kb * 8);
#pragma unroll
        for (int cc = 0; cc < 8; ++cc) {
          u32x4 wv = ld2x64(s_wst + (cb * 8 + cc) * 20 + kb * 8);
#pragma unroll
          for (int rr = 0; rr < 2; ++rr) acc[rr][cc] = dot8(xv[rr], wv, acc[rr][cc]);
        }
      }
    }
    __syncthreads();
#pragma unroll
    for (int rr = 0; rr < 2; ++rr)
#pragma unroll
      for (int cc = 0; cc < 8; ++cc) {
        float v = acc[rr][cc] + s_b2[cb * 8 + cc];
        s_d2[(rb * 2 + rr) * 128 + cb * 8 + cc] = (f16)fmaxf(v, 0.f);
      }
  }
  __syncthreads();

  // ---- L3: [64,128] @ [128->32] -> out (f32)
  {
    const int r = tid >> 3;
    const int cg = tid & 7;
    float acc[4] = {0.f, 0.f, 0.f, 0.f};
#pragma unroll
    for (int kb = 0; kb < 16; ++kb) {
      u32x4 xv = *(const u32x4*)(s_d2 + r * 128 + kb * 8);
#pragma unroll
      for (int cc = 0; cc < 4; ++cc) {
        u32x4 wv = *(const u32x4*)(s_w3 + (cg * 4 + cc) * 136 + kb * 8);
        acc[cc] = dot8(xv, wv, acc[cc]);
      }
    }
    f32x4 o;
    o.x = acc[0] + s_b3[cg * 4 + 0];
    o.y = acc[1] + s_b3[cg * 4 + 1];
    o.z = acc[2] + s_b3[cg * 4 + 2];
    o.w = acc[3] + s_b3[cg * 4 + 3];
    *(f32x4*)(out + (row0 + r) * 32 + cg * 4) = o;
  }
}

// ---------------------------------------------------------------------------
extern "C" void kernel_launch(void* const* d_in, const int* in_sizes, int n_in,
                              void* d_out, int out_size, void* d_ws, size_t ws_size,
                              hipStream_t stream) {
  const float* seq = (const float*)d_in[0];
  const float* mask = (const float*)d_in[1];
  const float* st = (const float*)d_in[2];
  const float* wx = (const float*)d_in[3];
  const float* wh = (const float*)d_in[4];
  const float* bz = (const float*)d_in[5];
  const float* w1 = (const float*)d_in[6];
  const float* b1 = (const float*)d_in[7];
  const float* w2 = (const float*)d_in[8];
  const float* b2 = (const float*)d_in[9];
  const float* w3 = (const float*)d_in[10];
  const float* b3 = (const float*)d_in[11];
  float* out = (float*)d_out;

  char* ws = (char*)d_ws;
  size_t off = 0;
  auto take = [&](size_t bytes) {
    void* p = ws + off;
    off = (off + bytes + 255) & ~(size_t)255;
    return p;
  };
  f16* wxT = (f16*)take((size_t)G4_ * NIN_ * 2);
  f16* whT = (f16*)take((size_t)G4_ * H_ * 2);
  f16* w1T = (f16*)take((size_t)256 * 256 * 2);
  f16* w2T = (f16*)take((size_t)128 * 256 * 2);
  f16* w3T = (f16*)take((size_t)32 * 128 * 2);
  f16* whF = (f16*)take((size_t)8 * 8 * 8 * 64 * 8 * 2);
  f16* wxF = (f16*)take((size_t)8 * 2 * 8 * 64 * 8 * 2);
  float* carry = (float*)take((size_t)NTASK * 512 * 4);
  f16* hsb = (f16*)take((size_t)NROWS * H_ * 2);
  (void)ws_size; (void)in_sizes; (void)n_in; (void)out_size;

  k_prep<<<dim3(512), dim3(256), 0, stream>>>(wx, wh, w1, w2, w3, wxT, whT, w1T, w2T, w3T,
                                              whF, wxF);
  k_phase1<<<dim3(P1_NWG), dim3(512), 0, stream>>>(seq, mask, whF, wxF, bz, hsb, carry);
  k_phase2<<<dim3(B_), dim3(512), 0, stream>>>(seq, mask, st, wxT, whT, bz, carry, hsb,
                                               out + (size_t)B_ * T_ * 32);
  k_head<<<dim3(NROWS / K3R), dim3(512), 0, stream>>>(hsb, w1T, b1, w2T, b2, w3T, b3, out);
}

// Round 6
// 1683.588 us; speedup vs baseline: 4.5628x; 1.3986x over previous
//
#include <hip/hip_runtime.h>
#include <hip/hip_fp16.h>
#include <stdint.h>

// ---------------------------------------------------------------------------
// StateRNN: masked LSTM (B=64,T=2048,H=256) + 3-layer MLP head.
// R6 design:
//  * phase1 (MFMA): CH=16, MT=32 tasks/WG (two 16-row M-tiles) -> 256 WGs
//    (all CUs), B-frags shared by 2 MFMAs (halves weight stream to 2.1GB),
//    nontemporal hs/seq to keep whF L2-resident.
//  * phase2 (MFMA, parallel): 8192 (b,ch) prefix tasks from phase-1 carries,
//    same structure as phase1, early-exit at group max prefix length.
//    Replaces the serial spilled-dot2 phase2 (R5's hidden ~hundreds of us).
//  * k_fix: rare-case exact cleanup (chunk with no reset, P=2^-16/chunk)
//    + writes states_out.
//  * head: fused 3-layer f16 MLP, 64-row tiles (unchanged).
// ---------------------------------------------------------------------------

typedef _Float16 f16;
typedef _Float16 f16x2 __attribute__((ext_vector_type(2)));
typedef _Float16 f16x8 __attribute__((ext_vector_type(8)));
typedef unsigned int u32;
typedef u32 u32x2 __attribute__((ext_vector_type(2)));
typedef u32 u32x4 __attribute__((ext_vector_type(4)));
typedef float f32x4 __attribute__((ext_vector_type(4)));

#define B_     64
#define T_     2048
#define NIN_   48
#define H_     256
#define G4_    1024
#define CH_    16
#define NCHUNK (T_ / CH_)       // 128
#define NTASK  (B_ * NCHUNK)    // 8192
#define MT     32               // tasks per WG (two mfma M-tiles)
#define P1_NWG (NTASK / MT)     // 256
#define NROWS  (B_ * T_)        // 131072

__device__ __forceinline__ f16x2 as_h2(u32 u) { return __builtin_bit_cast(f16x2, u); }

__device__ __forceinline__ float dot2(u32 a, u32 b, float c) {
#if __has_builtin(__builtin_amdgcn_fdot2)
  return __builtin_amdgcn_fdot2(as_h2(a), as_h2(b), c, false);
#else
  f16x2 ah = as_h2(a), bh = as_h2(b);
  return c + (float)ah.x * (float)bh.x + (float)ah.y * (float)bh.y;
#endif
}

__device__ __forceinline__ float dot8(u32x4 a, u32x4 b, float acc) {
  acc = dot2(a.x, b.x, acc);
  acc = dot2(a.y, b.y, acc);
  acc = dot2(a.z, b.z, acc);
  acc = dot2(a.w, b.w, acc);
  return acc;
}

__device__ __forceinline__ u32x4 ld2x64(const f16* p) {
  u32x2 a = *(const u32x2*)p;
  u32x2 b = *(const u32x2*)(p + 4);
  u32x4 r; r.x = a.x; r.y = a.y; r.z = b.x; r.w = b.y;
  return r;
}

__device__ __forceinline__ float mix8(f32x4 x0, f32x4 x1, u32x4 wv, float acc) {
  f16x2 p;
  p = as_h2(wv.x); acc = fmaf((float)p.x, x0.x, acc); acc = fmaf((float)p.y, x0.y, acc);
  p = as_h2(wv.y); acc = fmaf((float)p.x, x0.z, acc); acc = fmaf((float)p.y, x0.w, acc);
  p = as_h2(wv.z); acc = fmaf((float)p.x, x1.x, acc); acc = fmaf((float)p.y, x1.y, acc);
  p = as_h2(wv.w); acc = fmaf((float)p.x, x1.z, acc); acc = fmaf((float)p.y, x1.w, acc);
  return acc;
}

__device__ __forceinline__ float sigmf(float x) {
  return 1.0f / (1.0f + __builtin_exp2f(-1.44269504f * x));
}
__device__ __forceinline__ float tanhf_(float x) {
  return 2.0f / (1.0f + __builtin_exp2f(-2.88539008f * x)) - 1.0f;
}

// ---------------------------------------------------------------------------
// K0: weight conversion/shuffles (same layouts as R5; CH-independent).
// ---------------------------------------------------------------------------
__global__ void k_prep(const float* __restrict__ wx, const float* __restrict__ wh,
                       const float* __restrict__ w1, const float* __restrict__ w2,
                       const float* __restrict__ w3,
                       f16* __restrict__ wxT, f16* __restrict__ whT,
                       f16* __restrict__ w1T, f16* __restrict__ w2T,
                       f16* __restrict__ w3T,
                       f16* __restrict__ whF, f16* __restrict__ wxF) {
  const int i0 = blockIdx.x * blockDim.x + threadIdx.x;
  const int stride = gridDim.x * blockDim.x;
  for (int idx = i0; idx < NIN_ * G4_; idx += stride) {
    int k = idx / G4_, c = idx % G4_;
    wxT[c * NIN_ + k] = (f16)wx[idx];
  }
  for (int idx = i0; idx < H_ * G4_; idx += stride) {
    int k = idx / G4_, c = idx % G4_;
    whT[c * H_ + k] = (f16)wh[idx];
  }
  // whF: idx = ((((w*8+kt)*8+ct)*64)+l)*8 + j
  for (int idx = i0; idx < 8 * 8 * 8 * 64 * 8; idx += stride) {
    int j = idx & 7, l = (idx >> 3) & 63, ct = (idx >> 9) & 7;
    int kt = (idx >> 12) & 7, w = idx >> 15;
    int col = (ct >> 1) * 256 + w * 32 + (ct & 1) * 16 + (l & 15);
    int k = kt * 32 + (l >> 4) * 8 + j;
    whF[idx] = (f16)wh[k * G4_ + col];
  }
  // wxF: idx = ((((w*2+kt2)*8+ct)*64)+l)*8 + j  (k>=48 zero-padded)
  for (int idx = i0; idx < 8 * 2 * 8 * 64 * 8; idx += stride) {
    int j = idx & 7, l = (idx >> 3) & 63, ct = (idx >> 9) & 7;
    int kt2 = (idx >> 12) & 1, w = idx >> 13;
    int col = (ct >> 1) * 256 + w * 32 + (ct & 1) * 16 + (l & 15);
    int k = kt2 * 32 + (l >> 4) * 8 + j;
    wxF[idx] = (k < NIN_) ? (f16)wx[k * G4_ + col] : (f16)0.f;
  }
  for (int idx = i0; idx < 256 * 256; idx += stride) {
    int k = idx / 256, o = idx % 256;
    w1T[o * 256 + k] = (f16)w1[idx];
  }
  for (int idx = i0; idx < 256 * 128; idx += stride) {
    int k = idx / 128, o = idx % 128;
    w2T[o * 256 + k] = (f16)w2[idx];
  }
  for (int idx = i0; idx < 128 * 32; idx += stride) {
    int k = idx / 32, o = idx % 32;
    w3T[o * 128 + k] = (f16)w3[idx];
  }
}

// ---------------------------------------------------------------------------
// Phase 1 (MFMA): 256 WGs x 512 thr, 32 tasks each, 16 steps from zero state.
// ---------------------------------------------------------------------------
__global__ __launch_bounds__(512, 1) void k_phase1(
    const float* __restrict__ seq, const float* __restrict__ mask,
    const f16* __restrict__ whF, const f16* __restrict__ wxF,
    const float* __restrict__ bias,
    f16* __restrict__ hs, float* __restrict__ carry) {
  __shared__ __attribute__((aligned(16))) f16 s_h[MT * 256];     // 16KB, swizzled
  __shared__ __attribute__((aligned(16))) f16 s_x[8 * MT * 64];  // 32KB, swizzled
  __shared__ float s_m[CH_][MT];                                 // 2KB

  const int tid = threadIdx.x;
  const int wv = tid >> 6, l = tid & 63;
  const int l15 = l & 15, lq = l >> 4;
  const int gt0 = blockIdx.x * MT;
  const int b = gt0 >> 7, ch0 = gt0 & 127;
  char* s_hb = (char*)s_h;
  char* s_xb = (char*)s_x;

  // resident wx B-fragments
  f16x8 wxf[2][8];
#pragma unroll
  for (int kt2 = 0; kt2 < 2; ++kt2)
#pragma unroll
    for (int ct = 0; ct < 8; ++ct)
      wxf[kt2][ct] = *(const f16x8*)(wxF + ((((size_t)wv * 2 + kt2) * 8 + ct) * 64 + l) * 8);

  float biasv[8];
#pragma unroll
  for (int ct = 0; ct < 8; ++ct)
    biasv[ct] = bias[(ct >> 1) * 256 + wv * 32 + (ct & 1) * 16 + l15];

  // masks [lt][task]
  {
    const int task = tid & 31, lt = tid >> 5;
    s_m[lt][task] = mask[b * T_ + (ch0 + task) * CH_ + lt];
  }
  for (int i = tid; i < MT * 256 / 2; i += 512) ((u32*)s_h)[i] = 0u;

  float c_st[16], h_st[16];
#pragma unroll
  for (int i = 0; i < 16; ++i) { c_st[i] = 0.f; h_st[i] = 0.f; }

  const int unit0 = wv * 32 + l15;
  const int swzr = (l15 & 7) << 4;  // read-side swizzle (tasks m*16+l15 share &7)
  __syncthreads();

#pragma unroll 1
  for (int lt = 0; lt < CH_; ++lt) {
    // ---- every 8 steps: refill x window (rows = s8*32+task, padded K=64) ----
    if ((lt & 7) == 0) {
#pragma unroll
      for (int it = 0; it < 2; ++it) {
        const int row = (tid >> 2) + it * 128;
        const int kq = tid & 3;
        const int task = row & 31, s8 = row >> 5;
        const int t = (ch0 + task) * CH_ + lt + s8;
        f16 tmp[16];
        if (kq < 3) {
          const float* xp = seq + ((size_t)b * T_ + t) * NIN_ + kq * 16;
#pragma unroll
          for (int u = 0; u < 16; ++u) tmp[u] = (f16)__builtin_nontemporal_load(xp + u);
        } else {
#pragma unroll
          for (int u = 0; u < 16; ++u) tmp[u] = (f16)0.f;
        }
        const int base = row * 128 + kq * 32;
        const int swz = (task & 7) << 4;
        *(u32x4*)(s_xb + (base ^ swz)) = ((u32x4*)tmp)[0];
        *(u32x4*)(s_xb + ((base + 16) ^ swz)) = ((u32x4*)tmp)[1];
      }
      __syncthreads();
    }

    // ---- GEMM step: C = bias; += keep*h @ wh; += x @ wx ----
    f32x4 C[2][8];
#pragma unroll
    for (int m = 0; m < 2; ++m)
#pragma unroll
      for (int ct = 0; ct < 8; ++ct) {
        C[m][ct].x = biasv[ct]; C[m][ct].y = biasv[ct];
        C[m][ct].z = biasv[ct]; C[m][ct].w = biasv[ct];
      }

    const float ka0 = 1.0f - s_m[lt][l15];
    const float ka1 = 1.0f - s_m[lt][16 + l15];
    f16x8 ka0v, ka1v;
#pragma unroll
    for (int u = 0; u < 8; ++u) { ka0v[u] = (f16)ka0; ka1v[u] = (f16)ka1; }

#pragma unroll
    for (int kt = 0; kt < 8; ++kt) {
      f16x8 bv[8];
#pragma unroll
      for (int ct = 0; ct < 8; ++ct)
        bv[ct] = *(const f16x8*)(whF + ((((size_t)wv * 8 + kt) * 8 + ct) * 64 + l) * 8);
      u32x4 a0r = *(const u32x4*)(s_hb + l15 * 512 + (((kt * 32 + lq * 8) * 2) ^ swzr));
      u32x4 a1r = *(const u32x4*)(s_hb + (16 + l15) * 512 + (((kt * 32 + lq * 8) * 2) ^ swzr));
      f16x8 a0 = __builtin_bit_cast(f16x8, a0r) * ka0v;
      f16x8 a1 = __builtin_bit_cast(f16x8, a1r) * ka1v;
#pragma unroll
      for (int ct = 0; ct < 8; ++ct) {
        C[0][ct] = __builtin_amdgcn_mfma_f32_16x16x32_f16(a0, bv[ct], C[0][ct], 0, 0, 0);
        C[1][ct] = __builtin_amdgcn_mfma_f32_16x16x32_f16(a1, bv[ct], C[1][ct], 0, 0, 0);
      }
    }
    const int s8w = lt & 7;
#pragma unroll
    for (int kt2 = 0; kt2 < 2; ++kt2) {
      u32x4 a0r = *(const u32x4*)(
          s_xb + (((s8w * 32 + l15) * 128 + (kt2 * 32 + lq * 8) * 2) ^ swzr));
      u32x4 a1r = *(const u32x4*)(
          s_xb + (((s8w * 32 + 16 + l15) * 128 + (kt2 * 32 + lq * 8) * 2) ^ swzr));
      f16x8 a0 = __builtin_bit_cast(f16x8, a0r);
      f16x8 a1 = __builtin_bit_cast(f16x8, a1r);
#pragma unroll
      for (int ct = 0; ct < 8; ++ct) {
        C[0][ct] = __builtin_amdgcn_mfma_f32_16x16x32_f16(a0, wxf[kt2][ct], C[0][ct], 0, 0, 0);
        C[1][ct] = __builtin_amdgcn_mfma_f32_16x16x32_f16(a1, wxf[kt2][ct], C[1][ct], 0, 0, 0);
      }
    }
    __syncthreads();  // all A reads done before h overwrite

    // ---- epilogue: gates in-register ----
#pragma unroll
    for (int m = 0; m < 2; ++m)
#pragma unroll
      for (int s = 0; s < 2; ++s)
#pragma unroll
        for (int r = 0; r < 4; ++r) {
          const int ci = m * 8 + s * 4 + r;
          const int task = m * 16 + lq * 4 + r;
          const float keep = 1.0f - s_m[lt][task];
          float zi = C[m][0 + s][r], zf = C[m][2 + s][r];
          float zo = C[m][4 + s][r], zu = C[m][6 + s][r];
          float ig = sigmf(zi), fg = sigmf(zf), og = sigmf(zo), ug = tanhf_(zu);
          c_st[ci] = fg * (keep * c_st[ci]) + ig * ug;
          const float hn = og * tanhf_(c_st[ci]);
          h_st[ci] = hn;
          const int unit = unit0 + s * 16;
          *(f16*)(s_hb + task * 512 + ((unit * 2) ^ ((task & 7) << 4))) = (f16)hn;
          const int t = (ch0 + task) * CH_ + lt;
          __builtin_nontemporal_store((f16)hn, &hs[((size_t)t * B_ + b) * H_ + unit]);
        }
    __syncthreads();
  }

#pragma unroll
  for (int m = 0; m < 2; ++m)
#pragma unroll
    for (int s = 0; s < 2; ++s)
#pragma unroll
      for (int r = 0; r < 4; ++r) {
        const int gt = gt0 + m * 16 + lq * 4 + r;
        const int unit = unit0 + s * 16;
        carry[(size_t)gt * 512 + unit] = c_st[m * 8 + s * 4 + r];
        carry[(size_t)gt * 512 + 256 + unit] = h_st[m * 8 + s * 4 + r];
      }
}

// ---------------------------------------------------------------------------
// Phase 2 (MFMA, parallel prefix): 256 WGs x 32 (b,ch) tasks. Each task runs
// steps [0, r) of its chunk from the carry of chunk ch-1 (states_in for ch=0).
// Prefix steps have mask==0 (keep==1). Early-exit at group max r.
// Tasks whose source carry is bad (prev chunk had no reset) are fixed by k_fix.
// ---------------------------------------------------------------------------
__global__ __launch_bounds__(512, 1) void k_phase2(
    const float* __restrict__ seq, const float* __restrict__ mask,
    const float* __restrict__ states_in,
    const f16* __restrict__ whF, const f16* __restrict__ wxF,
    const float* __restrict__ bias,
    const float* __restrict__ carry,
    f16* __restrict__ hs, int* __restrict__ r_arr) {
  __shared__ __attribute__((aligned(16))) f16 s_h[MT * 256];
  __shared__ __attribute__((aligned(16))) f16 s_x[8 * MT * 64];
  __shared__ int s_ri[MT];
  __shared__ int s_maxr;

  const int tid = threadIdx.x;
  const int wv = tid >> 6, l = tid & 63;
  const int l15 = l & 15, lq = l >> 4;
  const int gt0 = blockIdx.x * MT;
  const int b = gt0 >> 7, ch0 = gt0 & 127;
  char* s_hb = (char*)s_h;
  char* s_xb = (char*)s_x;

  f16x8 wxf[2][8];
#pragma unroll
  for (int kt2 = 0; kt2 < 2; ++kt2)
#pragma unroll
    for (int ct = 0; ct < 8; ++ct)
      wxf[kt2][ct] = *(const f16x8*)(wxF + ((((size_t)wv * 2 + kt2) * 8 + ct) * 64 + l) * 8);

  float biasv[8];
#pragma unroll
  for (int ct = 0; ct < 8; ++ct)
    biasv[ct] = bias[(ct >> 1) * 256 + wv * 32 + (ct & 1) * 16 + l15];

  // r per task via ballot (task = tid>>4, lt = tid&15)
  {
    const int task = tid >> 4, lt = tid & 15;
    float mv = mask[b * T_ + (ch0 + task) * CH_ + lt];
    unsigned long long bal = __ballot(mv != 0.0f);
    unsigned field = (unsigned)(bal >> (lq * 16)) & 0xFFFFu;
    int rr = field ? (__ffs(field) - 1) : CH_;
    if (lt == 0) { s_ri[task] = rr; r_arr[gt0 + task] = rr; }
  }
  // h init from carry/states_in (swizzled)
  {
    const int task = tid >> 4, u0 = (tid & 15) * 16;
    const int gt = gt0 + task;
    const float* src = (gt & 127) ? (carry + (size_t)(gt - 1) * 512)
                                  : (states_in + (size_t)b * 512);
    f16 tmp[16];
#pragma unroll
    for (int u = 0; u < 16; ++u) tmp[u] = (f16)src[256 + u0 + u];
    const int base = task * 512 + u0 * 2;
    const int swz = (task & 7) << 4;
    *(u32x4*)(s_hb + (base ^ swz)) = ((u32x4*)tmp)[0];
    *(u32x4*)(s_hb + ((base + 16) ^ swz)) = ((u32x4*)tmp)[1];
  }
  __syncthreads();
  if (tid == 0) {
    int mx = 0;
    for (int i = 0; i < MT; ++i) mx = max(mx, s_ri[i]);
    s_maxr = mx;
  }
  // c init per lane
  const int unit0 = wv * 32 + l15;
  float c_st[16];
#pragma unroll
  for (int m = 0; m < 2; ++m)
#pragma unroll
    for (int s = 0; s < 2; ++s)
#pragma unroll
      for (int r = 0; r < 4; ++r) {
        const int task = m * 16 + lq * 4 + r;
        const int gt = gt0 + task;
        const float* src = (gt & 127) ? (carry + (size_t)(gt - 1) * 512)
                                      : (states_in + (size_t)b * 512);
        c_st[m * 8 + s * 4 + r] = src[unit0 + s * 16];
      }
  const int swzr = (l15 & 7) << 4;
  __syncthreads();
  const int maxr = s_maxr;

#pragma unroll 1
  for (int lt = 0; lt < maxr; ++lt) {
    if ((lt & 7) == 0) {
#pragma unroll
      for (int it = 0; it < 2; ++it) {
        const int row = (tid >> 2) + it * 128;
        const int kq = tid & 3;
        const int task = row & 31, s8 = row >> 5;
        const int t = (ch0 + task) * CH_ + lt + s8;
        f16 tmp[16];
        if (kq < 3) {
          const float* xp = seq + ((size_t)b * T_ + t) * NIN_ + kq * 16;
#pragma unroll
          for (int u = 0; u < 16; ++u) tmp[u] = (f16)__builtin_nontemporal_load(xp + u);
        } else {
#pragma unroll
          for (int u = 0; u < 16; ++u) tmp[u] = (f16)0.f;
        }
        const int base = row * 128 + kq * 32;
        const int swz = (task & 7) << 4;
        *(u32x4*)(s_xb + (base ^ swz)) = ((u32x4*)tmp)[0];
        *(u32x4*)(s_xb + ((base + 16) ^ swz)) = ((u32x4*)tmp)[1];
      }
      __syncthreads();
    }

    f32x4 C[2][8];
#pragma unroll
    for (int m = 0; m < 2; ++m)
#pragma unroll
      for (int ct = 0; ct < 8; ++ct) {
        C[m][ct].x = biasv[ct]; C[m][ct].y = biasv[ct];
        C[m][ct].z = biasv[ct]; C[m][ct].w = biasv[ct];
      }

#pragma unroll
    for (int kt = 0; kt < 8; ++kt) {
      f16x8 bv[8];
#pragma unroll
      for (int ct = 0; ct < 8; ++ct)
        bv[ct] = *(const f16x8*)(whF + ((((size_t)wv * 8 + kt) * 8 + ct) * 64 + l) * 8);
      u32x4 a0r = *(const u32x4*)(s_hb + l15 * 512 + (((kt * 32 + lq * 8) * 2) ^ swzr));
      u32x4 a1r = *(const u32x4*)(s_hb + (16 + l15) * 512 + (((kt * 32 + lq * 8) * 2) ^ swzr));
      f16x8 a0 = __builtin_bit_cast(f16x8, a0r);
      f16x8 a1 = __builtin_bit_cast(f16x8, a1r);
#pragma unroll
      for (int ct = 0; ct < 8; ++ct) {
        C[0][ct] = __builtin_amdgcn_mfma_f32_16x16x32_f16(a0, bv[ct], C[0][ct], 0, 0, 0);
        C[1][ct] = __builtin_amdgcn_mfma_f32_16x16x32_f16(a1, bv[ct], C[1][ct], 0, 0, 0);
      }
    }
    const int s8w = lt & 7;
#pragma unroll
    for (int kt2 = 0; kt2 < 2; ++kt2) {
      u32x4 a0r = *(const u32x4*)(
          s_xb + (((s8w * 32 + l15) * 128 + (kt2 * 32 + lq * 8) * 2) ^ swzr));
      u32x4 a1r = *(const u32x4*)(
          s_xb + (((s8w * 32 + 16 + l15) * 128 + (kt2 * 32 + lq * 8) * 2) ^ swzr));
      f16x8 a0 = __builtin_bit_cast(f16x8, a0r);
      f16x8 a1 = __builtin_bit_cast(f16x8, a1r);
#pragma unroll
      for (int ct = 0; ct < 8; ++ct) {
        C[0][ct] = __builtin_amdgcn_mfma_f32_16x16x32_f16(a0, wxf[kt2][ct], C[0][ct], 0, 0, 0);
        C[1][ct] = __builtin_amdgcn_mfma_f32_16x16x32_f16(a1, wxf[kt2][ct], C[1][ct], 0, 0, 0);
      }
    }
    __syncthreads();

#pragma unroll
    for (int m = 0; m < 2; ++m)
#pragma unroll
      for (int s = 0; s < 2; ++s)
#pragma unroll
        for (int r = 0; r < 4; ++r) {
          const int ci = m * 8 + s * 4 + r;
          const int task = m * 16 + lq * 4 + r;
          const bool active = lt < s_ri[task];
          float zi = C[m][0 + s][r], zf = C[m][2 + s][r];
          float zo = C[m][4 + s][r], zu = C[m][6 + s][r];
          float ig = sigmf(zi), fg = sigmf(zf), og = sigmf(zo), ug = tanhf_(zu);
          float cn = fg * c_st[ci] + ig * ug;
          float hn = og * tanhf_(cn);
          if (active) {
            c_st[ci] = cn;
            const int unit = unit0 + s * 16;
            *(f16*)(s_hb + task * 512 + ((unit * 2) ^ ((task & 7) << 4))) = (f16)hn;
            const int t = (ch0 + task) * CH_ + lt;
            __builtin_nontemporal_store((f16)hn, &hs[((size_t)t * B_ + b) * H_ + unit]);
          }
        }
    __syncthreads();
  }
}

// ---------------------------------------------------------------------------
// k_fix: 64 WGs (one per row). Handles the rare chunk-with-no-reset chains
// exactly (sequential recompute, streamed weights) and writes states_out.
// All fix steps have mask==0 (a no-reset chunk is all-zero mask; prefix
// steps are mask==0 by definition of r).
// ---------------------------------------------------------------------------
__global__ __launch_bounds__(512, 1) void k_fix(
    const float* __restrict__ seq, const float* __restrict__ states_in,
    const f16* __restrict__ wxT, const f16* __restrict__ whT,
    const float* __restrict__ bias,
    const float* __restrict__ carry, const int* __restrict__ r_arr,
    f16* __restrict__ hs, float* __restrict__ out_states) {
  __shared__ __attribute__((aligned(16))) f16 s_hf[H_];
  __shared__ __attribute__((aligned(16))) float s_x48[NIN_];
  __shared__ int s_rr[NCHUNK];

  const int tid = threadIdx.x;
  const int j = tid >> 1, q = tid & 1;
  const int b = blockIdx.x;

  if (tid < NCHUNK) s_rr[tid] = r_arr[b * NCHUNK + tid];
  __syncthreads();

  const float bia[4] = {bias[j], bias[H_ + j], bias[2 * H_ + j], bias[3 * H_ + j]};
  float cc = 0.f, hh = 0.f;
  bool have = false;

#pragma unroll 1
  for (int ch = 0; ch < NCHUNK; ++ch) {
    const int r = s_rr[ch];
    if (r < CH_ && !have) continue;  // fast path: nothing to fix

    if (r == CH_ && !have) {
      const float* src = ch ? (carry + (size_t)(b * NCHUNK + ch - 1) * 512)
                            : (states_in + (size_t)b * 512);
      cc = src[j];
      hh = src[256 + j];
      __syncthreads();
      if (tid < H_) s_hf[tid] = (f16)src[256 + tid];
      __syncthreads();
      have = true;
    }
    const int nsteps = (r == CH_) ? CH_ : r;
#pragma unroll 1
    for (int lt = 0; lt < nsteps; ++lt) {
      const int t = ch * CH_ + lt;
      if (tid < NIN_) s_x48[tid] = seq[((size_t)b * T_ + t) * NIN_ + tid];
      __syncthreads();
      float acc[4] = {0.f, 0.f, 0.f, 0.f};
      const f16* hrow = s_hf + q * 128;
#pragma unroll
      for (int kb = 0; kb < 16; ++kb) {
        u32x4 hv = *(const u32x4*)(hrow + kb * 8);
#pragma unroll
        for (int g = 0; g < 4; ++g)
          acc[g] = dot8(hv, *(const u32x4*)(whT + ((size_t)(g * H_ + j)) * H_ + q * 128 + kb * 8),
                        acc[g]);
      }
#pragma unroll
      for (int kb = 0; kb < 3; ++kb) {
        f32x4 x0 = *(const f32x4*)(s_x48 + q * 24 + kb * 8);
        f32x4 x1 = *(const f32x4*)(s_x48 + q * 24 + kb * 8 + 4);
#pragma unroll
        for (int g = 0; g < 4; ++g)
          acc[g] = mix8(x0, x1,
                        *(const u32x4*)(wxT + (size_t)(g * H_ + j) * NIN_ + q * 24 + kb * 8),
                        acc[g]);
      }
#pragma unroll
      for (int g = 0; g < 4; ++g) acc[g] += __shfl_xor(acc[g], 1);
      float ig = sigmf(acc[0] + bia[0]), fg = sigmf(acc[1] + bia[1]);
      float og = sigmf(acc[2] + bia[2]), ug = tanhf_(acc[3] + bia[3]);
      cc = fg * cc + ig * ug;
      const float hn = og * tanhf_(cc);
      hh = hn;
      __syncthreads();
      if (q == 0) {
        s_hf[j] = (f16)hn;
        hs[((size_t)t * B_ + b) * H_ + j] = (f16)hn;
      }
      __syncthreads();
    }
    if (r < CH_) have = false;  // truth merges with phase1 carries
  }

  if (have) {
    if (q == 0) {
      out_states[(size_t)b * 512 + j] = cc;
      out_states[(size_t)b * 512 + 256 + j] = hh;
    }
  } else {
    out_states[(size_t)b * 512 + tid] =
        carry[(size_t)(b * NCHUNK + NCHUNK - 1) * 512 + tid];
  }
}

// ---------------------------------------------------------------------------
// Head: fused 3-layer MLP over 64-row tiles of flat [T*B, H], 512 threads.
// ---------------------------------------------------------------------------
#define K3R 64
__global__ __launch_bounds__(512, 1) void k_head(
    const f16* __restrict__ hs,
    const f16* __restrict__ w1T, const float* __restrict__ b1,
    const f16* __restrict__ w2T, const float* __restrict__ b2,
    const f16* __restrict__ w3T, const float* __restrict__ b3,
    float* __restrict__ out) {
  __shared__ __attribute__((aligned(16))) f16 s_xx[K3R * 256];
  __shared__ __attribute__((aligned(16))) f16 s_d1[K3R * 256];
  __shared__ __attribute__((aligned(16))) f16 s_d2[K3R * 128];
  __shared__ __attribute__((aligned(16))) f16 s_wst[256 * 20];
  __shared__ __attribute__((aligned(16))) f16 s_w3[32 * 136];
  __shared__ float s_b1[256];
  __shared__ float s_b2[128];
  __shared__ float s_b3[32];

  const int tid = threadIdx.x;
  const size_t row0 = (size_t)blockIdx.x * K3R;

  {
    const u32x4* src = (const u32x4*)(hs + row0 * 256);
    u32x4* dst = (u32x4*)s_xx;
    for (int i = tid; i < K3R * 256 / 8; i += 512) dst[i] = src[i];
  }
  for (int i = tid; i < 32 * 128; i += 512) {
    int c = i / 128, k = i % 128;
    s_w3[c * 136 + k] = w3T[i];
  }
  if (tid < 256) s_b1[tid] = b1[tid];
  if (tid < 128) s_b2[tid] = b2[tid];
  if (tid < 32) s_b3[tid] = b3[tid];

  // ---- L1: [64,256] @ [256->256]
  {
    const int rb = tid >> 5;
    const int cb = tid & 31;
    float acc[4][8];
#pragma unroll
    for (int rr = 0; rr < 4; ++rr)
#pragma unroll
      for (int cc = 0; cc < 8; ++cc) acc[rr][cc] = 0.f;
    for (int ks = 0; ks < 16; ++ks) {
      __syncthreads();
      {
        const int c = tid >> 1, half = tid & 1;
        u32x4 a = *(const u32x4*)(w1T + (size_t)c * 256 + ks * 16 + half * 8);
        u32x2* wdst = (u32x2*)(s_wst + c * 20 + half * 8);
        u32x2 p0; p0.x = a.x; p0.y = a.y;
        u32x2 p1; p1.x = a.z; p1.y = a.w;
        wdst[0] = p0; wdst[1] = p1;
      }
      __syncthreads();
#pragma unroll
      for (int kb = 0; kb < 2; ++kb) {
        u32x4 xv[4];
#pragma unroll
        for (int rr = 0; rr < 4; ++rr)
          xv[rr] = *(const u32x4*)(s_xx + (rb * 4 + rr) * 256 + ks * 16 + kb * 8);
#pragma unroll
        for (int cc = 0; cc < 8; ++cc) {
          u32x4 wv = ld2x64(s_wst + (cb * 8 + cc) * 20 + kb * 8);
#pragma unroll
          for (int rr = 0; rr < 4; ++rr) acc[rr][cc] = dot8(xv[rr], wv, acc[rr][cc]);
        }
      }
    }
    __syncthreads();
#pragma unroll
    for (int rr = 0; rr < 4; ++rr)
#pragma unroll
      for (int cc = 0; cc < 8; ++cc) {
        float v = acc[rr][cc] + s_b1[cb * 8 + cc];
        s_d1[(rb * 4 + rr) * 256 + cb * 8 + cc] = (f16)fmaxf(v, 0.f);
      }
  }
  __syncthreads();

  // ---- L2: [64,256] @ [256->128]
  {
    const int rb = tid >> 4;
    const int cb = tid & 15;
    float acc[2][8];
#pragma unroll
    for (int rr = 0; rr < 2; ++rr)
#pragma unroll
      for (int cc = 0; cc < 8; ++cc) acc[rr][cc] = 0.f;
    for (int ks = 0; ks < 16; ++ks) {
      __syncthreads();
      if (tid < 256) {
        const int c = tid >> 1, half = tid & 1;
        u32x4 a = *(const u32x4*)(w2T + (size_t)c * 256 + ks * 16 + half * 8);
        u32x2* wdst = (u32x2*)(s_wst + c * 20 + half * 8);
        u32x2 p0; p0.x = a.x; p0.y = a.y;
        u32x2 p1; p1.x = a.z; p1.y = a.w;
        wdst[0] = p0; wdst[1] = p1;
      }
      __syncthreads();
#pragma unroll
      for (int kb = 0; kb < 2; ++kb) {
        u32x4 xv[2];
#pragma unroll
        for (int rr = 0; rr < 2; ++rr)
          xv[rr] = *(const u32x4*)(s_d1 + (rb * 2 + rr) * 256 + ks * 16 + kb * 8);
#pragma unroll
        for (int cc = 0; cc < 8; ++cc) {
          u32x4 wv = ld2x64(s_wst + (cb * 8 + cc) * 20 + kb * 8);
#pragma unroll
          for (int rr = 0; rr < 2; ++rr) acc[rr][cc] = dot8(xv[rr], wv, acc[rr][cc]);
        }
      }
    }
    __syncthreads();
#pragma unroll
    for (int rr = 0; rr < 2; ++rr)
#pragma unroll
      for (int cc = 0; cc < 8; ++cc) {
        float v = acc[rr][cc] + s_b2[cb * 8 + cc];
        s_d2[(rb * 2 + rr) * 128 + cb * 8 + cc] = (f16)fmaxf(v, 0.f);
      }
  }
  __syncthreads();

  // ---- L3: [64,128] @ [128->32] -> out (f32)
  {
    const int r = tid >> 3;
    const int cg = tid & 7;
    float acc[4] = {0.f, 0.f, 0.f, 0.f};
#pragma unroll
    for (int kb = 0; kb < 16; ++kb) {
      u32x4 xv = *(const u32x4*)(s_d2 + r * 128 + kb * 8);
#pragma unroll
      for (int cc = 0; cc < 4; ++cc) {
        u32x4 wv = *(const u32x4*)(s_w3 + (cg * 4 + cc) * 136 + kb * 8);
        acc[cc] = dot8(xv, wv, acc[cc]);
      }
    }
    f32x4 o;
    o.x = acc[0] + s_b3[cg * 4 + 0];
    o.y = acc[1] + s_b3[cg * 4 + 1];
    o.z = acc[2] + s_b3[cg * 4 + 2];
    o.w = acc[3] + s_b3[cg * 4 + 3];
    *(f32x4*)(out + (row0 + r) * 32 + cg * 4) = o;
  }
}

// ---------------------------------------------------------------------------
extern "C" void kernel_launch(void* const* d_in, const int* in_sizes, int n_in,
                              void* d_out, int out_size, void* d_ws, size_t ws_size,
                              hipStream_t stream) {
  const float* seq = (const float*)d_in[0];
  const float* mask = (const float*)d_in[1];
  const float* st = (const float*)d_in[2];
  const float* wx = (const float*)d_in[3];
  const float* wh = (const float*)d_in[4];
  const float* bz = (const float*)d_in[5];
  const float* w1 = (const float*)d_in[6];
  const float* b1 = (const float*)d_in[7];
  const float* w2 = (const float*)d_in[8];
  const float* b2 = (const float*)d_in[9];
  const float* w3 = (const float*)d_in[10];
  const float* b3 = (const float*)d_in[11];
  float* out = (float*)d_out;

  char* ws = (char*)d_ws;
  size_t off = 0;
  auto take = [&](size_t bytes) {
    void* p = ws + off;
    off = (off + bytes + 255) & ~(size_t)255;
    return p;
  };
  f16* wxT = (f16*)take((size_t)G4_ * NIN_ * 2);
  f16* whT = (f16*)take((size_t)G4_ * H_ * 2);
  f16* w1T = (f16*)take((size_t)256 * 256 * 2);
  f16* w2T = (f16*)take((size_t)128 * 256 * 2);
  f16* w3T = (f16*)take((size_t)32 * 128 * 2);
  f16* whF = (f16*)take((size_t)8 * 8 * 8 * 64 * 8 * 2);
  f16* wxF = (f16*)take((size_t)8 * 2 * 8 * 64 * 8 * 2);
  float* carry = (float*)take((size_t)NTASK * 512 * 4);
  int* r_arr = (int*)take((size_t)NTASK * 4);
  f16* hsb = (f16*)take((size_t)NROWS * H_ * 2);
  (void)ws_size; (void)in_sizes; (void)n_in; (void)out_size;

  k_prep<<<dim3(512), dim3(256), 0, stream>>>(wx, wh, w1, w2, w3, wxT, whT, w1T, w2T, w3T,
                                              whF, wxF);
  k_phase1<<<dim3(P1_NWG), dim3(512), 0, stream>>>(seq, mask, whF, wxF, bz, hsb, carry);
  k_phase2<<<dim3(P1_NWG), dim3(512), 0, stream>>>(seq, mask, st, whF, wxF, bz, carry, hsb,
                                                   r_arr);
  k_fix<<<dim3(B_), dim3(512), 0, stream>>>(seq, st, wxT, whT, bz, carry, r_arr, hsb,
                                            out + (size_t)B_ * T_ * 32);
  k_head<<<dim3(NROWS / K3R), dim3(512), 0, stream>>>(hsb, w1T, b1, w2T, b2, w3T, b3, out);
}